// Round 10
// baseline (141.442 us; speedup 1.0000x reference)
//
#include <hip/hip_runtime.h>
#include <hip/hip_bf16.h>

#define NN 262144
#define CC 4096
#define NBLK 64              // sort blocks
#define PPB (NN / NBLK)      // 4096 points per sort block
#define NT2 (NN / 128)       // 2048 dense 128-row tiles
#define SLOTS 3              // per-cluster pooling slots (j>=2 -> atomic into slot 2)

typedef __attribute__((ext_vector_type(8))) short bf16x8;
typedef __attribute__((ext_vector_type(4))) float f32x4;

// bf16 pair pack via HW cvt (RNE)
__device__ __forceinline__ unsigned pk2(float a, float b) {
  __hip_bfloat16 ha = __float2bfloat16(a);
  __hip_bfloat16 hb = __float2bfloat16(b);
  unsigned short ua, ub;
  __builtin_memcpy(&ua, &ha, 2);
  __builtin_memcpy(&ub, &hb, 2);
  return (unsigned)ua | ((unsigned)ub << 16);
}

// ---------- fused init: blocks 0..63 = histogram ; 64..123 = weight prepack ----------
__global__ __launch_bounds__(256) void k_init(
    const int* __restrict__ cluster, unsigned* __restrict__ hist2d,
    const float* __restrict__ eW2, const float* __restrict__ W1,
    const float* __restrict__ W2, unsigned* __restrict__ packE,
    unsigned* __restrict__ pack1, unsigned* __restrict__ pack2)
{
  __shared__ unsigned h[CC];
  const int t = threadIdx.x, b = blockIdx.x;
  if (b < NBLK) {                                      // histogram
    for (int q = t; q < CC; q += 256) h[q] = 0u;
    __syncthreads();
    const int base = b * PPB;
#pragma unroll 4
    for (int k = 0; k < PPB; k += 256) atomicAdd(&h[cluster[base + k + t]], 1u);
    __syncthreads();
    for (int q = t; q < CC; q += 256) hist2d[b * CC + q] = h[q];
    return;
  }
  const int id = (b - NBLK) * 256 + t;                 // prepack
  if (id < 1024) {                                     // packE
    const int nt = id >> 8, l = (id >> 2) & 63, v = id & 3;
    const int k0 = (l >> 4) * 8 + 2 * v, col = nt * 16 + (l & 15);
    packE[id] = pk2(eW2[k0 * 64 + col], eW2[(k0 + 1) * 64 + col]);
  } else if (id < 1024 + 6144) {                       // pack1
    const int j = id - 1024;
    const int kk = j >> 11, nt = (j >> 8) & 7, l = (j >> 2) & 63, v = j & 3;
    const int col = nt * 16 + (l & 15);
    float vals[2];
#pragma unroll
    for (int hh = 0; hh < 2; ++hh) {
      const int k = kk * 32 + (l >> 4) * 8 + 2 * v + hh;
      vals[hh] = (k < 64) ? W1[(3 + k) * 128 + col]
               : (k < 67) ? W1[(k - 64) * 128 + col] : 0.f;
    }
    pack1[j] = pk2(vals[0], vals[1]);
  } else {                                             // pack2 (interleaved k)
    const int j = id - (1024 + 6144);
    const int kk = j >> 11, nt = (j >> 8) & 7, l = (j >> 2) & 63, v = j & 3;
    const int col = nt * 16 + (l & 15);
    const int k0 = kk * 32 + (l >> 4) * 4 + v;
    pack2[j] = pk2(W2[k0 * 128 + col], W2[(k0 + 16) * 128 + col]);
  }
}

// ---------- scan_a: blocks 0..15 scan ; 16..111 zero pse/psf ----------
#define ZERO_F4 589824        // (pse 786432 + psf 1572864) u32 / 4
__global__ __launch_bounds__(256) void k_scan_a(
    const unsigned* __restrict__ hist2d, unsigned* __restrict__ base2d,
    unsigned* __restrict__ totals, float4* __restrict__ zbase)
{
  const int t = threadIdx.x, b = blockIdx.x;
  if (b < 16) {
    const int c = b * 256 + t;
    unsigned acc = 0;
#pragma unroll 4
    for (int bb = 0; bb < NBLK; ++bb) {
      const unsigned v = hist2d[bb * CC + c];
      base2d[bb * CC + c] = acc;
      acc += v;
    }
    totals[c] = acc;
  } else {
    const int zb = b - 16;                             // 96 zero blocks
    const float4 z = {0.f, 0.f, 0.f, 0.f};
#pragma unroll 5
    for (int q = 0; q < 25; ++q) {
      const int idx = (zb * 25 + q) * 256 + t;
      if (idx < ZERO_F4) zbase[idx] = z;
    }
  }
}

// ---------- scatter (inline cstart scan; packed perm|cid output) ----------
__global__ __launch_bounds__(256) void k_scatter(
    const int* __restrict__ cluster, const unsigned* __restrict__ base2d,
    const unsigned* __restrict__ totals, unsigned* __restrict__ permcid,
    unsigned* __restrict__ cstart_g)
{
  __shared__ unsigned cur[CC];
  __shared__ unsigned part[256];
  const int t = threadIdx.x, b = blockIdx.x;
  unsigned loc[16];
  unsigned s = 0;
#pragma unroll
  for (int q = 0; q < 16; ++q) { loc[q] = s; s += totals[t * 16 + q]; }
  part[t] = s;
  __syncthreads();
  for (int off = 1; off < 256; off <<= 1) {
    const unsigned v = (t >= off) ? part[t - off] : 0u;
    __syncthreads();
    part[t] += v;
    __syncthreads();
  }
  const unsigned baset = part[t] - s;
#pragma unroll
  for (int q = 0; q < 16; ++q) {
    const unsigned cs = baset + loc[q];
    cur[t * 16 + q] = base2d[b * CC + t * 16 + q] + cs;
    if (b == 0) cstart_g[t * 16 + q] = cs;
  }
  __syncthreads();
  const int base = b * PPB;
#pragma unroll 4
  for (int k = 0; k < PPB; k += 256) {
    const int i = base + k + t;
    const int c = cluster[i];
    const unsigned pos = atomicAdd(&cur[c], 1u);
    permcid[pos] = (unsigned)i | ((unsigned)c << 18);
  }
}

// ---------- tile kernel 1: enc MLP (M=128) + segmented pool -> pse ----------
__global__ __launch_bounds__(256) void k_enc_t(
    const float* __restrict__ pts, const unsigned* __restrict__ permcid,
    const unsigned* __restrict__ cstart,
    const float* __restrict__ eW1, const float* __restrict__ eb1,
    const float* __restrict__ eb2, const unsigned* __restrict__ packE,
    float* __restrict__ pse)
{
  __shared__ float P4[128 * 4];
  __shared__ unsigned h1s[128 * 20];    // [128][40 bf16] pad
  __shared__ unsigned long long flagw[2];
  __shared__ int seg_r0[129];
  __shared__ int seg_cid[128];
  __shared__ int seg_j[128];
  __shared__ int nseg_s;
  const int t = threadIdx.x;
  const int lane = t & 63, w = t >> 6;
  const int g = lane >> 4, ln15 = lane & 15;
  const int b = blockIdx.x;

  int cid = -1; bool flag = false;
  if (t < 128) {    // flags + P4 staging (waves 0,1 fully active)
    const unsigned pc = permcid[b * 128 + t];
    cid = (int)(pc >> 18);
    const int prevcid = (t == 0) ? -1 : (int)(permcid[b * 128 + t - 1] >> 18);
    flag = (t == 0) || (prevcid != cid);
    const unsigned long long m = __ballot(flag);
    if ((t & 63) == 0) flagw[t >> 6] = m;
    const int i = (int)(pc & 0x3FFFFu);
    P4[t * 4 + 0] = pts[i * 3 + 0];
    P4[t * 4 + 1] = pts[i * 3 + 1];
    P4[t * 4 + 2] = pts[i * 3 + 2];
    P4[t * 4 + 3] = 0.f;
  }
  __syncthreads();
  if (t < 128) {    // 2-wave segment table
    const unsigned long long m0 = flagw[0], m1 = flagw[1];
    const int wv = t >> 6, ln = t & 63;
    const unsigned long long mym = wv ? m1 : m0;
    const int rank = (int)__popcll(mym & ((1ull << ln) - 1ull)) +
                     (wv ? (int)__popcll(m0) : 0);
    if (flag) {
      seg_r0[rank] = t;
      seg_cid[rank] = cid;
      seg_j[rank] = b - (int)(cstart[cid] >> 7);
    }
    if (t == 0) {
      const int ns = (int)(__popcll(m0) + __popcll(m1));
      nseg_s = ns;
      seg_r0[ns] = 128;
    }
  }
  {   // h1 = relu(P @ eW1 + eb1) -> LDS bf16 ; 2 threads/row, 16 cols each
    const int r = t >> 1, sg = t & 1;
    const float p0 = P4[r * 4], p1 = P4[r * 4 + 1], p2 = P4[r * 4 + 2];
    unsigned wv4[8];
#pragma unroll
    for (int u = 0; u < 8; ++u) {
      float hv[2];
#pragma unroll
      for (int hh = 0; hh < 2; ++hh) {
        const int c2 = sg * 16 + 2 * u + hh;
        hv[hh] = fmaxf(fmaf(p2, eW1[64 + c2],
                       fmaf(p1, eW1[32 + c2],
                       fmaf(p0, eW1[c2], eb1[c2]))), 0.f);
      }
      wv4[u] = pk2(hv[0], hv[1]);
    }
    uint4 s0; s0.x = wv4[0]; s0.y = wv4[1]; s0.z = wv4[2]; s0.w = wv4[3];
    uint4 s1; s1.x = wv4[4]; s1.y = wv4[5]; s1.z = wv4[6]; s1.w = wv4[7];
    *reinterpret_cast<uint4*>(&h1s[r * 20 + sg * 8 + 0]) = s0;
    *reinterpret_cast<uint4*>(&h1s[r * 20 + sg * 8 + 4]) = s1;
  }
  __syncthreads();
  {   // enc MFMA: wave w -> cols 16w..16w+15 ; M=128, K=32; segmented pool
    const int col = w * 16 + ln15;
    const bf16x8 bfr = *reinterpret_cast<const bf16x8*>(&packE[(w * 64 + lane) * 4]);
    const float bias = eb2[col];
    f32x4 acc[8];
#pragma unroll
    for (int m = 0; m < 8; ++m) acc[m] = f32x4{bias, bias, bias, bias};
#pragma unroll
    for (int m = 0; m < 8; ++m) {
      const bf16x8 a = *reinterpret_cast<const bf16x8*>(&h1s[(16 * m + ln15) * 20 + g * 4]);
      acc[m] = __builtin_amdgcn_mfma_f32_16x16x32_bf16(a, bfr, acc[m], 0, 0, 0);
    }
    const int nseg = nseg_s;
    for (int s = 0; s < nseg; ++s) {
      const int r0 = seg_r0[s], r1 = seg_r0[s + 1];
      float v = 0.f;
#pragma unroll
      for (int m = 0; m < 8; ++m)
#pragma unroll
        for (int q = 0; q < 4; ++q) {
          const int row = 16 * m + 4 * g + q;
          const bool in = (row >= r0) & (row < r1);
          v = fmaxf(v, in ? fmaxf(acc[m][q], 0.f) : 0.f);
        }
      v = fmaxf(v, __shfl_xor(v, 16, 64));
      v = fmaxf(v, __shfl_xor(v, 32, 64));
      if (lane < 16) {
        const int c = seg_cid[s], j = seg_j[s];
        if (j < SLOTS - 1)
          pse[((size_t)c * SLOTS + j) * 64 + col] = v;
        else
          atomicMax((int*)&pse[((size_t)c * SLOTS + (SLOTS - 1)) * 64 + col],
                    __float_as_int(v));
      }
    }
  }
}

// ---------- cproj: nm = max-combine(pse) ; cp = b1 + nm @ W1[67:131] ----------
__global__ __launch_bounds__(256) void k_cproj2(
    const float* __restrict__ pse, const float* __restrict__ W1,
    const float* __restrict__ b1, float* __restrict__ cproj)
{
  __shared__ float nm2[2][64];
  const int t = threadIdx.x, b = blockIdx.x;      // 2 clusters per block
  if (t < 128) {
    const int rr = t >> 6, col = t & 63;
    const float* p = pse + ((size_t)(b * 2 + rr) * SLOTS) * 64 + col;
    nm2[rr][col] = fmaxf(fmaxf(p[0], p[64]), p[128]);
  }
  __syncthreads();
  const int rr = t >> 7, col = t & 127;
  const float* __restrict__ Wd = W1 + 67 * 128;
  float a = b1[col];
#pragma unroll 4
  for (int j = 0; j < 16; ++j) {
    const f32x4 nv = *reinterpret_cast<const f32x4*>(&nm2[rr][4 * j]);
    a = fmaf(nv[0], Wd[(4 * j + 0) * 128 + col], a);
    a = fmaf(nv[1], Wd[(4 * j + 1) * 128 + col], a);
    a = fmaf(nv[2], Wd[(4 * j + 2) * 128 + col], a);
    a = fmaf(nv[3], Wd[(4 * j + 3) * 128 + col], a);
  }
  cproj[(size_t)(b * 2 + rr) * 128 + col] = a;
}

// ---------- tile kernel 2: fc1 + fc2 (M=128) + segmented pool -> psf ----------
__global__ __launch_bounds__(256) void k_fc_t(
    const float* __restrict__ pts, const float* __restrict__ feat,
    const unsigned* __restrict__ permcid, const unsigned* __restrict__ cstart,
    const float* __restrict__ b2, const float* __restrict__ cproj,
    const unsigned* __restrict__ pack1, const unsigned* __restrict__ pack2,
    float* __restrict__ psf)
{
  __shared__ unsigned buf[128 * 68];  // X phase: [128][52] ; E1 phase: [128][68]
  __shared__ unsigned long long flagw[2];
  __shared__ int cid_l[128];
  __shared__ int seg_r0[129];
  __shared__ int seg_cid[128];
  __shared__ int seg_j[128];
  __shared__ int nseg_s;
  const int t = threadIdx.x;
  const int lane = t & 63, w = t >> 6;
  const int g = lane >> 4, ln15 = lane & 15;
  const int b = blockIdx.x;

  int cid = -1; bool flag = false;
  if (t < 128) {    // flags (waves 0,1)
    const unsigned pc = permcid[b * 128 + t];
    cid = (int)(pc >> 18);
    cid_l[t] = cid;
    const int prevcid = (t == 0) ? -1 : (int)(permcid[b * 128 + t - 1] >> 18);
    flag = (t == 0) || (prevcid != cid);
    const unsigned long long m = __ballot(flag);
    if ((t & 63) == 0) flagw[t >> 6] = m;
  }
  {   // stage X (bf16): 2 threads/row; sg=0 -> feat[0:32), sg=1 -> feat[32:64)+pts+0
    const int r = t >> 1, sg = t & 1;
    const int i = (int)(permcid[b * 128 + r] & 0x3FFFFu);
    const float4* __restrict__ fp = reinterpret_cast<const float4*>(&feat[(size_t)i * 64 + sg * 32]);
    const float4 f0 = fp[0], f1 = fp[1], f2 = fp[2], f3 = fp[3];
    const float4 f4 = fp[4], f5 = fp[5], f6 = fp[6], f7 = fp[7];
    uint4 s0v, s1v, s2v, s3v;
    s0v.x = pk2(f0.x, f0.y); s0v.y = pk2(f0.z, f0.w);
    s0v.z = pk2(f1.x, f1.y); s0v.w = pk2(f1.z, f1.w);
    s1v.x = pk2(f2.x, f2.y); s1v.y = pk2(f2.z, f2.w);
    s1v.z = pk2(f3.x, f3.y); s1v.w = pk2(f3.z, f3.w);
    s2v.x = pk2(f4.x, f4.y); s2v.y = pk2(f4.z, f4.w);
    s2v.z = pk2(f5.x, f5.y); s2v.w = pk2(f5.z, f5.w);
    s3v.x = pk2(f6.x, f6.y); s3v.y = pk2(f6.z, f6.w);
    s3v.z = pk2(f7.x, f7.y); s3v.w = pk2(f7.z, f7.w);
    unsigned* __restrict__ dst = &buf[r * 52 + sg * 16];
    *reinterpret_cast<uint4*>(dst + 0)  = s0v;
    *reinterpret_cast<uint4*>(dst + 4)  = s1v;
    *reinterpret_cast<uint4*>(dst + 8)  = s2v;
    *reinterpret_cast<uint4*>(dst + 12) = s3v;
    if (sg) {   // X cols 64..66 = pts, 67..95 = 0
      uint4 pw;
      pw.x = pk2(pts[i * 3 + 0], pts[i * 3 + 1]);
      pw.y = pk2(pts[i * 3 + 2], 0.f);
      pw.z = 0u; pw.w = 0u;
      uint4 zz; zz.x = zz.y = zz.z = zz.w = 0u;
      *reinterpret_cast<uint4*>(&buf[r * 52 + 32]) = pw;
      *reinterpret_cast<uint4*>(&buf[r * 52 + 36]) = zz;
      *reinterpret_cast<uint4*>(&buf[r * 52 + 40]) = zz;
      *reinterpret_cast<uint4*>(&buf[r * 52 + 44]) = zz;
    }
  }
  __syncthreads();
  if (t < 128) {    // 2-wave segment table (runs alongside fc1 below in schedule)
    const unsigned long long m0 = flagw[0], m1 = flagw[1];
    const int wv = t >> 6, ln = t & 63;
    const unsigned long long mym = wv ? m1 : m0;
    const int rank = (int)__popcll(mym & ((1ull << ln) - 1ull)) +
                     (wv ? (int)__popcll(m0) : 0);
    if (flag) {
      seg_r0[rank] = t;
      seg_cid[rank] = cid;
      seg_j[rank] = b - (int)(cstart[cid] >> 7);
    }
    if (t == 0) {
      const int ns = (int)(__popcll(m0) + __popcll(m1));
      nseg_s = ns;
      seg_r0[ns] = 128;
    }
  }

  const int colA = w * 32 + ln15, colB = colA + 16;
  f32x4 acc0[8], acc1[8];
  {   // fc1 MFMA: K=96, acc starts at 0; cproj added after (loads hoist over MFMA)
#pragma unroll
    for (int m = 0; m < 8; ++m) {
      acc0[m] = f32x4{0.f, 0.f, 0.f, 0.f};
      acc1[m] = f32x4{0.f, 0.f, 0.f, 0.f};
    }
#pragma unroll
    for (int kk = 0; kk < 3; ++kk) {
      const bf16x8 bf0 = *reinterpret_cast<const bf16x8*>(&pack1[((kk * 8 + 2 * w + 0) * 64 + lane) * 4]);
      const bf16x8 bf1 = *reinterpret_cast<const bf16x8*>(&pack1[((kk * 8 + 2 * w + 1) * 64 + lane) * 4]);
#pragma unroll
      for (int m = 0; m < 8; ++m) {
        const bf16x8 a = *reinterpret_cast<const bf16x8*>(&buf[(16 * m + ln15) * 52 + kk * 16 + g * 4]);
        acc0[m] = __builtin_amdgcn_mfma_f32_16x16x32_bf16(a, bf0, acc0[m], 0, 0, 0);
        acc1[m] = __builtin_amdgcn_mfma_f32_16x16x32_bf16(a, bf1, acc1[m], 0, 0, 0);
      }
    }
#pragma unroll
    for (int m = 0; m < 8; ++m)
#pragma unroll
      for (int q = 0; q < 4; ++q) {
        const int row = 16 * m + 4 * g + q;
        const int cc = cid_l[row];
        acc0[m][q] += cproj[(size_t)cc * 128 + colA];
        acc1[m][q] += cproj[(size_t)cc * 128 + colB];
      }
  }
  __syncthreads();   // all X reads done; buf can be overwritten
  {   // E1 = relu(fc1) as interleaved bf16 pairs (col, col+16)
#pragma unroll
    for (int m = 0; m < 8; ++m)
#pragma unroll
      for (int q = 0; q < 4; ++q) {
        const int row = 16 * m + 4 * g + q;
        buf[row * 68 + w * 16 + ln15] =
            pk2(fmaxf(acc0[m][q], 0.f), fmaxf(acc1[m][q], 0.f));
      }
  }
  __syncthreads();
  {   // fc2 MFMA: K=128 (interleaved k matches pack2)
    const float bb0 = b2[colA], bb1 = b2[colB];
#pragma unroll
    for (int m = 0; m < 8; ++m) {
      acc0[m] = f32x4{bb0, bb0, bb0, bb0};
      acc1[m] = f32x4{bb1, bb1, bb1, bb1};
    }
#pragma unroll
    for (int kk = 0; kk < 4; ++kk) {
      const bf16x8 bf0 = *reinterpret_cast<const bf16x8*>(&pack2[((kk * 8 + 2 * w + 0) * 64 + lane) * 4]);
      const bf16x8 bf1 = *reinterpret_cast<const bf16x8*>(&pack2[((kk * 8 + 2 * w + 1) * 64 + lane) * 4]);
#pragma unroll
      for (int m = 0; m < 8; ++m) {
        const bf16x8 a = *reinterpret_cast<const bf16x8*>(&buf[(16 * m + ln15) * 68 + kk * 16 + g * 4]);
        acc0[m] = __builtin_amdgcn_mfma_f32_16x16x32_bf16(a, bf0, acc0[m], 0, 0, 0);
        acc1[m] = __builtin_amdgcn_mfma_f32_16x16x32_bf16(a, bf1, acc1[m], 0, 0, 0);
      }
    }
  }
  {   // segmented pool -> psf
    const int nseg = nseg_s;
    for (int s = 0; s < nseg; ++s) {
      const int r0 = seg_r0[s], r1 = seg_r0[s + 1];
      float v0 = 0.f, v1 = 0.f;
#pragma unroll
      for (int m = 0; m < 8; ++m)
#pragma unroll
        for (int q = 0; q < 4; ++q) {
          const int row = 16 * m + 4 * g + q;
          const bool in = (row >= r0) & (row < r1);
          v0 = fmaxf(v0, in ? fmaxf(acc0[m][q], 0.f) : 0.f);
          v1 = fmaxf(v1, in ? fmaxf(acc1[m][q], 0.f) : 0.f);
        }
      v0 = fmaxf(v0, __shfl_xor(v0, 16, 64)); v0 = fmaxf(v0, __shfl_xor(v0, 32, 64));
      v1 = fmaxf(v1, __shfl_xor(v1, 16, 64)); v1 = fmaxf(v1, __shfl_xor(v1, 32, 64));
      if (lane < 16) {
        const int c = seg_cid[s], j = seg_j[s];
        if (j < SLOTS - 1) {
          psf[((size_t)c * SLOTS + j) * 128 + colA] = v0;
          psf[((size_t)c * SLOTS + j) * 128 + colB] = v1;
        } else {
          atomicMax((int*)&psf[((size_t)c * SLOTS + (SLOTS - 1)) * 128 + colA], __float_as_int(v0));
          atomicMax((int*)&psf[((size_t)c * SLOTS + (SLOTS - 1)) * 128 + colB], __float_as_int(v1));
        }
      }
    }
  }
}

// ---------- global stack: 1024 blocks x 4 clusters, register-blocked f32 ----------
__global__ __launch_bounds__(256) void k_glob(
    const float* __restrict__ psf, const float* __restrict__ G1,
    const float* __restrict__ gb1, const float* __restrict__ G2,
    const float* __restrict__ gb2, float* __restrict__ out)
{
  __shared__ float pooled[4][128];
  __shared__ float tg[4][128];
  const int t = threadIdx.x, b = blockIdx.x;     // 1024 blocks x 4 clusters
  const int c0 = b * 4;
#pragma unroll
  for (int q = 0; q < 2; ++q) {                  // combine SLOTS -> pooled
    const int idx = q * 256 + t;
    const int cc = idx >> 7, col = idx & 127;
    const float* p = psf + (size_t)(c0 + cc) * (SLOTS * 128) + col;
    pooled[cc][col] = fmaxf(fmaxf(p[0], p[128]), p[256]);
  }
  __syncthreads();
  {   // g1: col = t&127; hi = t>>7 selects cluster pair {2hi, 2hi+1}
    const int col = t & 127, hi = t >> 7;
    float a0 = gb1[col], a1 = a0;
#pragma unroll 4
    for (int k = 0; k < 128; ++k) {
      const float wv = G1[k * 128 + col];
      a0 = fmaf(pooled[hi * 2 + 0][k], wv, a0);
      a1 = fmaf(pooled[hi * 2 + 1][k], wv, a1);
    }
    tg[hi * 2 + 0][col] = fmaxf(a0, 0.f);
    tg[hi * 2 + 1][col] = fmaxf(a1, 0.f);
  }
  __syncthreads();
  {   // g2: col = t, 4 clusters; G2 value loaded once per k (LDS reads broadcast)
    float o[4];
#pragma unroll
    for (int q = 0; q < 4; ++q) o[q] = gb2[t];
#pragma unroll 2
    for (int k = 0; k < 128; ++k) {
      const float wv = G2[k * 256 + t];
#pragma unroll
      for (int q = 0; q < 4; ++q) o[q] = fmaf(tg[q][k], wv, o[q]);
    }
#pragma unroll
    for (int q = 0; q < 4; ++q)
      out[(size_t)(c0 + q) * 256 + t] = fmaxf(o[q], 0.f);
  }
}

extern "C" void kernel_launch(void* const* d_in, const int* in_sizes, int n_in,
                              void* d_out, int out_size, void* d_ws, size_t ws_size,
                              hipStream_t stream)
{
  (void)in_sizes; (void)n_in; (void)out_size; (void)ws_size;
  const float* pts  = (const float*)d_in[0];
  const float* feat = (const float*)d_in[1];
  const int*   clus = (const int*)  d_in[2];
  const float* eW1  = (const float*)d_in[3];
  const float* eb1  = (const float*)d_in[4];
  const float* eW2  = (const float*)d_in[5];
  const float* eb2  = (const float*)d_in[6];
  const float* W1   = (const float*)d_in[7];
  const float* b1   = (const float*)d_in[8];
  const float* W2   = (const float*)d_in[9];
  const float* b2   = (const float*)d_in[10];
  const float* G1   = (const float*)d_in[11];
  const float* gb1  = (const float*)d_in[12];
  const float* G2   = (const float*)d_in[13];
  const float* gb2  = (const float*)d_in[14];
  float* out = (float*)d_out;

  // ws layout (u32 offsets):
  //   hist2d @0 (262144) | base2d @262144 (262144)
  //   totals @524288 (4096) | cstart @528384 (4096)
  //   permcid @532480 (262144)
  //   packE @794624 (1024) | pack1 @795648 (6144) | pack2 @801792 (8192)
  //   cproj @809984 (524288 f32)
  //   ZERO range (scan_a): pse @1334272 (786432 f32) | psf @2120704 (1572864 f32)
  unsigned* ws      = (unsigned*)d_ws;
  unsigned* hist2d  = ws;
  unsigned* base2d  = ws + 262144;
  unsigned* totals  = ws + 524288;
  unsigned* cstart  = ws + 528384;
  unsigned* permcid = ws + 532480;
  unsigned* packE   = ws + 794624;
  unsigned* pack1   = ws + 795648;
  unsigned* pack2   = ws + 801792;
  float*    cproj   = (float*)(ws + 809984);
  float*    pse     = (float*)(ws + 1334272);
  float*    psf     = (float*)(ws + 2120704);

  k_init   <<<NBLK + 60, 256, 0, stream>>>(clus, hist2d, eW2, W1, W2,
                                           packE, pack1, pack2);
  k_scan_a <<<112, 256, 0, stream>>>(hist2d, base2d, totals, (float4*)pse);
  k_scatter<<<NBLK, 256, 0, stream>>>(clus, base2d, totals, permcid, cstart);
  k_enc_t  <<<NT2, 256, 0, stream>>>(pts, permcid, cstart, eW1, eb1, eb2,
                                     packE, pse);
  k_cproj2 <<<CC / 2, 256, 0, stream>>>(pse, W1, b1, cproj);
  k_fc_t   <<<NT2, 256, 0, stream>>>(pts, feat, permcid, cstart, b2, cproj,
                                     pack1, pack2, psf);
  k_glob   <<<1024, 256, 0, stream>>>(psf, G1, gb1, G2, gb2, out);
}

// Round 11
// 111.582 us; speedup vs baseline: 1.2676x; 1.2676x over previous
//
#include <hip/hip_runtime.h>
#include <hip/hip_bf16.h>

#define NN 262144
#define CC 4096
#define NBLK 64              // sort blocks
#define PPB (NN / NBLK)      // 4096 points per sort block
#define NT (NN / 64)         // 4096 dense 64-row tiles
#define SLOTS 3              // per-cluster pooling slots (j>=2 -> atomic into slot 2)

typedef __attribute__((ext_vector_type(8))) short bf16x8;
typedef __attribute__((ext_vector_type(4))) float f32x4;

// bf16 pair pack via HW cvt (RNE)
__device__ __forceinline__ unsigned pk2(float a, float b) {
  __hip_bfloat16 ha = __float2bfloat16(a);
  __hip_bfloat16 hb = __float2bfloat16(b);
  unsigned short ua, ub;
  __builtin_memcpy(&ua, &ha, 2);
  __builtin_memcpy(&ub, &hb, 2);
  return (unsigned)ua | ((unsigned)ub << 16);
}

// ---------- fused init: blocks 0..63 = histogram ; 64..123 = weight prepack ----------
__global__ __launch_bounds__(256) void k_init(
    const int* __restrict__ cluster, unsigned* __restrict__ hist2d,
    const float* __restrict__ eW2, const float* __restrict__ W1,
    const float* __restrict__ W2, unsigned* __restrict__ packE,
    unsigned* __restrict__ pack1, unsigned* __restrict__ pack2)
{
  __shared__ unsigned h[CC];
  const int t = threadIdx.x, b = blockIdx.x;
  if (b < NBLK) {                                      // histogram
    for (int q = t; q < CC; q += 256) h[q] = 0u;
    __syncthreads();
    const int base = b * PPB;
#pragma unroll 4
    for (int k = 0; k < PPB; k += 256) atomicAdd(&h[cluster[base + k + t]], 1u);
    __syncthreads();
    for (int q = t; q < CC; q += 256) hist2d[b * CC + q] = h[q];
    return;
  }
  const int id = (b - NBLK) * 256 + t;                 // prepack
  if (id < 1024) {                                     // packE
    const int nt = id >> 8, l = (id >> 2) & 63, v = id & 3;
    const int k0 = (l >> 4) * 8 + 2 * v, col = nt * 16 + (l & 15);
    packE[id] = pk2(eW2[k0 * 64 + col], eW2[(k0 + 1) * 64 + col]);
  } else if (id < 1024 + 6144) {                       // pack1
    const int j = id - 1024;
    const int kk = j >> 11, nt = (j >> 8) & 7, l = (j >> 2) & 63, v = j & 3;
    const int col = nt * 16 + (l & 15);
    float vals[2];
#pragma unroll
    for (int hh = 0; hh < 2; ++hh) {
      const int k = kk * 32 + (l >> 4) * 8 + 2 * v + hh;
      vals[hh] = (k < 64) ? W1[(3 + k) * 128 + col]
               : (k < 67) ? W1[(k - 64) * 128 + col] : 0.f;
    }
    pack1[j] = pk2(vals[0], vals[1]);
  } else {                                             // pack2 (interleaved k)
    const int j = id - (1024 + 6144);
    const int kk = j >> 11, nt = (j >> 8) & 7, l = (j >> 2) & 63, v = j & 3;
    const int col = nt * 16 + (l & 15);
    const int k0 = kk * 32 + (l >> 4) * 4 + v;
    pack2[j] = pk2(W2[k0 * 128 + col], W2[(k0 + 16) * 128 + col]);
  }
}

// ---------- scan_a: blocks 0..15 scan ; 16..111 zero pse/psf ----------
#define ZERO_F4 589824        // (pse 786432 + psf 1572864) u32 / 4
__global__ __launch_bounds__(256) void k_scan_a(
    const unsigned* __restrict__ hist2d, unsigned* __restrict__ base2d,
    unsigned* __restrict__ totals, float4* __restrict__ zbase)
{
  const int t = threadIdx.x, b = blockIdx.x;
  if (b < 16) {
    const int c = b * 256 + t;
    unsigned acc = 0;
#pragma unroll 4
    for (int bb = 0; bb < NBLK; ++bb) {
      const unsigned v = hist2d[bb * CC + c];
      base2d[bb * CC + c] = acc;
      acc += v;
    }
    totals[c] = acc;
  } else {
    const int zb = b - 16;                             // 96 zero blocks
    const float4 z = {0.f, 0.f, 0.f, 0.f};
#pragma unroll 5
    for (int q = 0; q < 25; ++q) {
      const int idx = (zb * 25 + q) * 256 + t;
      if (idx < ZERO_F4) zbase[idx] = z;
    }
  }
}

// ---------- scatter (inline cstart scan; packed perm|cid output) ----------
__global__ __launch_bounds__(256) void k_scatter(
    const int* __restrict__ cluster, const unsigned* __restrict__ base2d,
    const unsigned* __restrict__ totals, unsigned* __restrict__ permcid,
    unsigned* __restrict__ cstart_g)
{
  __shared__ unsigned cur[CC];
  __shared__ unsigned part[256];
  const int t = threadIdx.x, b = blockIdx.x;
  unsigned loc[16];
  unsigned s = 0;
#pragma unroll
  for (int q = 0; q < 16; ++q) { loc[q] = s; s += totals[t * 16 + q]; }
  part[t] = s;
  __syncthreads();
  for (int off = 1; off < 256; off <<= 1) {
    const unsigned v = (t >= off) ? part[t - off] : 0u;
    __syncthreads();
    part[t] += v;
    __syncthreads();
  }
  const unsigned baset = part[t] - s;
#pragma unroll
  for (int q = 0; q < 16; ++q) {
    const unsigned cs = baset + loc[q];
    cur[t * 16 + q] = base2d[b * CC + t * 16 + q] + cs;
    if (b == 0) cstart_g[t * 16 + q] = cs;
  }
  __syncthreads();
  const int base = b * PPB;
#pragma unroll 4
  for (int k = 0; k < PPB; k += 256) {
    const int i = base + k + t;
    const int c = cluster[i];
    const unsigned pos = atomicAdd(&cur[c], 1u);
    permcid[pos] = (unsigned)i | ((unsigned)c << 18);
  }
}

// ---------- tile kernel 1: enc MLP + segmented pool -> pse (plain stores) ----------
__global__ __launch_bounds__(256) void k_enc_t(
    const float* __restrict__ pts, const unsigned* __restrict__ permcid,
    const unsigned* __restrict__ cstart,
    const float* __restrict__ eW1, const float* __restrict__ eb1,
    const float* __restrict__ eb2, const unsigned* __restrict__ packE,
    float* __restrict__ pse)
{
  __shared__ float P4[64 * 4];
  __shared__ unsigned h1s[64 * 20];     // [64][40 bf16] pad -> 2-way max
  __shared__ int seg_r0[65];
  __shared__ int seg_cid[64];
  __shared__ int seg_j[64];
  __shared__ int nseg_s;
  const int t = threadIdx.x;
  const int lane = t & 63, w = t >> 6;
  const int g = lane >> 4, ln15 = lane & 15;
  const int b = blockIdx.x;

  if (w == 0) {   // segment table from sorted cluster ids
    const unsigned pc = permcid[b * 64 + t];
    const int cid = (int)(pc >> 18);
    const int prevcid = (t == 0) ? -1 : (int)(permcid[b * 64 + t - 1] >> 18);
    const bool flag = (t == 0) || (prevcid != cid);
    const unsigned long long mask = __ballot(flag);
    const int rank = (int)__popcll(mask & ((1ull << t) - 1ull));
    if (flag) {
      seg_r0[rank] = t;
      seg_cid[rank] = cid;
      seg_j[rank] = b - (int)(cstart[cid] >> 6);
    }
    if (t == 0) {
      const int ns = (int)__popcll(mask);
      nseg_s = ns;
      seg_r0[ns] = 64;
    }
    const int i = (int)(pc & 0x3FFFFu);
    P4[t * 4 + 0] = pts[i * 3 + 0];
    P4[t * 4 + 1] = pts[i * 3 + 1];
    P4[t * 4 + 2] = pts[i * 3 + 2];
    P4[t * 4 + 3] = 0.f;
  }
  __syncthreads();
  {   // h1 = relu(P @ eW1 + eb1) -> LDS bf16 ; thread: row t>>2, 8 cols
    const int r = t >> 2, qq = t & 3;
    const float p0 = P4[r * 4], p1 = P4[r * 4 + 1], p2 = P4[r * 4 + 2];
    unsigned wv[4];
#pragma unroll
    for (int u = 0; u < 4; ++u) {
      float hv[2];
#pragma unroll
      for (int hh = 0; hh < 2; ++hh) {
        const int cc2 = qq * 8 + 2 * u + hh;
        hv[hh] = fmaxf(fmaf(p2, eW1[64 + cc2],
                       fmaf(p1, eW1[32 + cc2],
                       fmaf(p0, eW1[cc2], eb1[cc2]))), 0.f);
      }
      wv[u] = pk2(hv[0], hv[1]);
    }
    uint4 st; st.x = wv[0]; st.y = wv[1]; st.z = wv[2]; st.w = wv[3];
    *reinterpret_cast<uint4*>(&h1s[r * 20 + qq * 4]) = st;
  }
  __syncthreads();
  {   // enc MFMA: wave w -> cols 16w..16w+15 ; M=64, K=32; segmented pool
    const int col = w * 16 + ln15;
    const bf16x8 bfr = *reinterpret_cast<const bf16x8*>(&packE[(w * 64 + lane) * 4]);
    const float bias = eb2[col];
    f32x4 acc[4];
#pragma unroll
    for (int m = 0; m < 4; ++m) acc[m] = f32x4{bias, bias, bias, bias};
#pragma unroll
    for (int m = 0; m < 4; ++m) {
      const bf16x8 a = *reinterpret_cast<const bf16x8*>(&h1s[(16 * m + ln15) * 20 + g * 4]);
      acc[m] = __builtin_amdgcn_mfma_f32_16x16x32_bf16(a, bfr, acc[m], 0, 0, 0);
    }
    const int nseg = nseg_s;
    for (int s = 0; s < nseg; ++s) {
      const int r0 = seg_r0[s], r1 = seg_r0[s + 1];
      float v = 0.f;    // v >= 0 throughout; final v = max(0, max acc) = relu-max
#pragma unroll
      for (int m = 0; m < 4; ++m) {
        if (r0 < 16 * (m + 1) && r1 > 16 * m) {   // uniform m-block overlap skip
#pragma unroll
          for (int q = 0; q < 4; ++q) {
            const int row = 16 * m + 4 * g + q;
            const bool in = (row >= r0) & (row < r1);
            v = fmaxf(v, in ? acc[m][q] : 0.f);
          }
        }
      }
      v = fmaxf(v, __shfl_xor(v, 16, 64));
      v = fmaxf(v, __shfl_xor(v, 32, 64));
      if (lane < 16) {
        const int c = seg_cid[s], j = seg_j[s];
        if (j < SLOTS - 1)
          pse[((size_t)c * SLOTS + j) * 64 + col] = v;
        else
          atomicMax((int*)&pse[((size_t)c * SLOTS + (SLOTS - 1)) * 64 + col],
                    __float_as_int(v));
      }
    }
  }
}

// ---------- cproj: nm = max-combine(pse) ; cp = b1 + nm @ W1[67:131] ----------
__global__ __launch_bounds__(256) void k_cproj2(
    const float* __restrict__ pse, const float* __restrict__ W1,
    const float* __restrict__ b1, float* __restrict__ cproj)
{
  __shared__ float nm2[2][64];
  const int t = threadIdx.x, b = blockIdx.x;      // 2 clusters per block
  if (t < 128) {
    const int rr = t >> 6, col = t & 63;
    const float* p = pse + ((size_t)(b * 2 + rr) * SLOTS) * 64 + col;
    nm2[rr][col] = fmaxf(fmaxf(p[0], p[64]), p[128]);
  }
  __syncthreads();
  const int rr = t >> 7, col = t & 127;
  const float* __restrict__ Wd = W1 + 67 * 128;
  float a = b1[col];
#pragma unroll 4
  for (int j = 0; j < 16; ++j) {
    const f32x4 nv = *reinterpret_cast<const f32x4*>(&nm2[rr][4 * j]);
    a = fmaf(nv[0], Wd[(4 * j + 0) * 128 + col], a);
    a = fmaf(nv[1], Wd[(4 * j + 1) * 128 + col], a);
    a = fmaf(nv[2], Wd[(4 * j + 2) * 128 + col], a);
    a = fmaf(nv[3], Wd[(4 * j + 3) * 128 + col], a);
  }
  cproj[(size_t)(b * 2 + rr) * 128 + col] = a;
}

// ---------- tile kernel 2: fc1 + fc2 + segmented pool -> psf ----------
__global__ __launch_bounds__(256) void k_fc_t(
    const float* __restrict__ pts, const float* __restrict__ feat,
    const unsigned* __restrict__ permcid, const unsigned* __restrict__ cstart,
    const float* __restrict__ b2, const float* __restrict__ cproj,
    const unsigned* __restrict__ pack1, const unsigned* __restrict__ pack2,
    float* __restrict__ psf)
{
  __shared__ unsigned buf[64 * 68];   // X phase: [64][52] ; E1 phase: [64][68]
  __shared__ float cpd[8][128];
  __shared__ int ridx_l[64];
  __shared__ int cid_l[64];
  __shared__ int seg_r0[65];
  __shared__ int seg_cid[64];
  __shared__ int seg_j[64];
  __shared__ int nseg_s;
  const int t = threadIdx.x;
  const int lane = t & 63, w = t >> 6;
  const int g = lane >> 4, ln15 = lane & 15;
  const int b = blockIdx.x;

  if (w == 0) {   // segment table + per-row segment index
    const unsigned pc = permcid[b * 64 + t];
    const int cid = (int)(pc >> 18);
    cid_l[t] = cid;
    const int prevcid = (t == 0) ? -1 : (int)(permcid[b * 64 + t - 1] >> 18);
    const bool flag = (t == 0) || (prevcid != cid);
    const unsigned long long mask = __ballot(flag);
    const int rank = (int)__popcll(mask & ((1ull << t) - 1ull));
    ridx_l[t] = (int)__popcll(mask & ((2ull << t) - 1ull)) - 1;
    if (flag) {
      seg_r0[rank] = t;
      seg_cid[rank] = cid;
      seg_j[rank] = b - (int)(cstart[cid] >> 6);
    }
    if (t == 0) {
      const int ns = (int)__popcll(mask);
      nseg_s = ns;
      seg_r0[ns] = 64;
    }
  }
  {   // stage X feat cols (bf16): 4 threads/row, 16 cols each
    const int r = t >> 2, seg = t & 3;
    const int i = (int)(permcid[b * 64 + r] & 0x3FFFFu);
    const float4* __restrict__ fp = reinterpret_cast<const float4*>(&feat[(size_t)i * 64 + seg * 16]);
    const float4 f0 = fp[0], f1 = fp[1], f2 = fp[2], f3 = fp[3];
    uint4 s0v, s1v;
    s0v.x = pk2(f0.x, f0.y); s0v.y = pk2(f0.z, f0.w);
    s0v.z = pk2(f1.x, f1.y); s0v.w = pk2(f1.z, f1.w);
    s1v.x = pk2(f2.x, f2.y); s1v.y = pk2(f2.z, f2.w);
    s1v.z = pk2(f3.x, f3.y); s1v.w = pk2(f3.z, f3.w);
    *reinterpret_cast<uint4*>(&buf[r * 52 + seg * 8 + 0]) = s0v;
    *reinterpret_cast<uint4*>(&buf[r * 52 + seg * 8 + 4]) = s1v;
  }
  if (t < 64) {   // X cols 64..66 = pts, 67..95 = 0
    const int i = (int)(permcid[b * 64 + t] & 0x3FFFFu);
    uint4 pw;
    pw.x = pk2(pts[i * 3 + 0], pts[i * 3 + 1]);
    pw.y = pk2(pts[i * 3 + 2], 0.f);
    pw.z = 0u; pw.w = 0u;
    uint4 zz; zz.x = zz.y = zz.z = zz.w = 0u;
    *reinterpret_cast<uint4*>(&buf[t * 52 + 32]) = pw;
    *reinterpret_cast<uint4*>(&buf[t * 52 + 36]) = zz;
    *reinterpret_cast<uint4*>(&buf[t * 52 + 40]) = zz;
    *reinterpret_cast<uint4*>(&buf[t * 52 + 44]) = zz;
  }
  __syncthreads();
  {   // stage distinct cproj rows (fallback to global for seg idx >= 8)
    const int nseg = nseg_s;
    const int lim = (nseg < 8) ? nseg : 8;
    for (int s = t >> 7; s < lim; s += 2)
      cpd[s][t & 127] = cproj[(size_t)seg_cid[s] * 128 + (t & 127)];
  }
  __syncthreads();

  const int colA = w * 32 + ln15, colB = colA + 16;
  f32x4 acc0[4], acc1[4];
  {   // fc1 init: per-row cluster projection
    const int nseg = nseg_s;
    if (nseg <= 2) {
      const float cA0 = cpd[0][colA], cA1 = cpd[0][colB];
      const float cB0 = (nseg == 2) ? cpd[1][colA] : cA0;
      const float cB1 = (nseg == 2) ? cpd[1][colB] : cA1;
      const int rb = (nseg == 2) ? seg_r0[1] : 64;
#pragma unroll
      for (int m = 0; m < 4; ++m)
#pragma unroll
        for (int q = 0; q < 4; ++q) {
          const int row = 16 * m + 4 * g + q;
          acc0[m][q] = (row < rb) ? cA0 : cB0;
          acc1[m][q] = (row < rb) ? cA1 : cB1;
        }
    } else {
#pragma unroll
      for (int m = 0; m < 4; ++m)
#pragma unroll
        for (int q = 0; q < 4; ++q) {
          const int row = 16 * m + 4 * g + q;
          const int idx = ridx_l[row];
          if (idx < 8) {
            acc0[m][q] = cpd[idx][colA];
            acc1[m][q] = cpd[idx][colB];
          } else {
            const int cc = cid_l[row];
            acc0[m][q] = cproj[(size_t)cc * 128 + colA];
            acc1[m][q] = cproj[(size_t)cc * 128 + colB];
          }
        }
    }
  }
  {   // fc1 MFMA: K=96
#pragma unroll
    for (int kk = 0; kk < 3; ++kk) {
      const bf16x8 bf0 = *reinterpret_cast<const bf16x8*>(&pack1[((kk * 8 + 2 * w + 0) * 64 + lane) * 4]);
      const bf16x8 bf1 = *reinterpret_cast<const bf16x8*>(&pack1[((kk * 8 + 2 * w + 1) * 64 + lane) * 4]);
#pragma unroll
      for (int m = 0; m < 4; ++m) {
        const bf16x8 a = *reinterpret_cast<const bf16x8*>(&buf[(16 * m + ln15) * 52 + kk * 16 + g * 4]);
        acc0[m] = __builtin_amdgcn_mfma_f32_16x16x32_bf16(a, bf0, acc0[m], 0, 0, 0);
        acc1[m] = __builtin_amdgcn_mfma_f32_16x16x32_bf16(a, bf1, acc1[m], 0, 0, 0);
      }
    }
  }
  __syncthreads();   // all X reads done; buf can be overwritten
  {   // E1 = relu(fc1) as interleaved bf16 pairs: u32 (col, col+16) -> conflict-free
#pragma unroll
    for (int m = 0; m < 4; ++m)
#pragma unroll
      for (int q = 0; q < 4; ++q) {
        const int row = 16 * m + 4 * g + q;
        buf[row * 68 + w * 16 + ln15] =
            pk2(fmaxf(acc0[m][q], 0.f), fmaxf(acc1[m][q], 0.f));
      }
  }
  __syncthreads();
  {   // fc2 MFMA: K=128 (interleaved k matches pack2)
    const float bb0 = b2[colA], bb1 = b2[colB];
#pragma unroll
    for (int m = 0; m < 4; ++m) {
      acc0[m] = f32x4{bb0, bb0, bb0, bb0};
      acc1[m] = f32x4{bb1, bb1, bb1, bb1};
    }
#pragma unroll
    for (int kk = 0; kk < 4; ++kk) {
      const bf16x8 bf0 = *reinterpret_cast<const bf16x8*>(&pack2[((kk * 8 + 2 * w + 0) * 64 + lane) * 4]);
      const bf16x8 bf1 = *reinterpret_cast<const bf16x8*>(&pack2[((kk * 8 + 2 * w + 1) * 64 + lane) * 4]);
#pragma unroll
      for (int m = 0; m < 4; ++m) {
        const bf16x8 a = *reinterpret_cast<const bf16x8*>(&buf[(16 * m + ln15) * 68 + kk * 16 + g * 4]);
        acc0[m] = __builtin_amdgcn_mfma_f32_16x16x32_bf16(a, bf0, acc0[m], 0, 0, 0);
        acc1[m] = __builtin_amdgcn_mfma_f32_16x16x32_bf16(a, bf1, acc1[m], 0, 0, 0);
      }
    }
  }
  {   // segmented pool -> psf (m-block skip + relu folded into max-with-0-init)
    const int nseg = nseg_s;
    for (int s = 0; s < nseg; ++s) {
      const int r0 = seg_r0[s], r1 = seg_r0[s + 1];
      float v0 = 0.f, v1 = 0.f;
#pragma unroll
      for (int m = 0; m < 4; ++m) {
        if (r0 < 16 * (m + 1) && r1 > 16 * m) {   // uniform m-block overlap skip
#pragma unroll
          for (int q = 0; q < 4; ++q) {
            const int row = 16 * m + 4 * g + q;
            const bool in = (row >= r0) & (row < r1);
            v0 = fmaxf(v0, in ? acc0[m][q] : 0.f);
            v1 = fmaxf(v1, in ? acc1[m][q] : 0.f);
          }
        }
      }
      v0 = fmaxf(v0, __shfl_xor(v0, 16, 64)); v0 = fmaxf(v0, __shfl_xor(v0, 32, 64));
      v1 = fmaxf(v1, __shfl_xor(v1, 16, 64)); v1 = fmaxf(v1, __shfl_xor(v1, 32, 64));
      if (lane < 16) {
        const int c = seg_cid[s], j = seg_j[s];
        if (j < SLOTS - 1) {
          psf[((size_t)c * SLOTS + j) * 128 + colA] = v0;
          psf[((size_t)c * SLOTS + j) * 128 + colB] = v1;
        } else {
          atomicMax((int*)&psf[((size_t)c * SLOTS + (SLOTS - 1)) * 128 + colA], __float_as_int(v0));
          atomicMax((int*)&psf[((size_t)c * SLOTS + (SLOTS - 1)) * 128 + colB], __float_as_int(v1));
        }
      }
    }
  }
}

// ---------- global stack: 1024 blocks x 4 clusters, register-blocked f32 ----------
__global__ __launch_bounds__(256) void k_glob(
    const float* __restrict__ psf, const float* __restrict__ G1,
    const float* __restrict__ gb1, const float* __restrict__ G2,
    const float* __restrict__ gb2, float* __restrict__ out)
{
  __shared__ float pooled[4][128];
  __shared__ float tg[4][128];
  const int t = threadIdx.x, b = blockIdx.x;     // 1024 blocks x 4 clusters
  const int c0 = b * 4;
#pragma unroll
  for (int q = 0; q < 2; ++q) {                  // combine SLOTS -> pooled
    const int idx = q * 256 + t;
    const int cc = idx >> 7, col = idx & 127;
    const float* p = psf + (size_t)(c0 + cc) * (SLOTS * 128) + col;
    pooled[cc][col] = fmaxf(fmaxf(p[0], p[128]), p[256]);
  }
  __syncthreads();
  {   // g1: col = t&127; hi = t>>7 selects cluster pair {2hi, 2hi+1}
    const int col = t & 127, hi = t >> 7;
    float a0 = gb1[col], a1 = a0;
#pragma unroll 4
    for (int k = 0; k < 128; ++k) {
      const float wv = G1[k * 128 + col];
      a0 = fmaf(pooled[hi * 2 + 0][k], wv, a0);
      a1 = fmaf(pooled[hi * 2 + 1][k], wv, a1);
    }
    tg[hi * 2 + 0][col] = fmaxf(a0, 0.f);
    tg[hi * 2 + 1][col] = fmaxf(a1, 0.f);
  }
  __syncthreads();
  {   // g2: col = t, 4 clusters; G2 value loaded once per k (LDS reads broadcast)
    float o[4];
#pragma unroll
    for (int q = 0; q < 4; ++q) o[q] = gb2[t];
#pragma unroll 2
    for (int k = 0; k < 128; ++k) {
      const float wv = G2[k * 256 + t];
#pragma unroll
      for (int q = 0; q < 4; ++q) o[q] = fmaf(tg[q][k], wv, o[q]);
    }
#pragma unroll
    for (int q = 0; q < 4; ++q)
      out[(size_t)(c0 + q) * 256 + t] = fmaxf(o[q], 0.f);
  }
}

extern "C" void kernel_launch(void* const* d_in, const int* in_sizes, int n_in,
                              void* d_out, int out_size, void* d_ws, size_t ws_size,
                              hipStream_t stream)
{
  (void)in_sizes; (void)n_in; (void)out_size; (void)ws_size;
  const float* pts  = (const float*)d_in[0];
  const float* feat = (const float*)d_in[1];
  const int*   clus = (const int*)  d_in[2];
  const float* eW1  = (const float*)d_in[3];
  const float* eb1  = (const float*)d_in[4];
  const float* eW2  = (const float*)d_in[5];
  const float* eb2  = (const float*)d_in[6];
  const float* W1   = (const float*)d_in[7];
  const float* b1   = (const float*)d_in[8];
  const float* W2   = (const float*)d_in[9];
  const float* b2   = (const float*)d_in[10];
  const float* G1   = (const float*)d_in[11];
  const float* gb1  = (const float*)d_in[12];
  const float* G2   = (const float*)d_in[13];
  const float* gb2  = (const float*)d_in[14];
  float* out = (float*)d_out;

  // ws layout (u32 offsets):
  //   hist2d @0 (262144) | base2d @262144 (262144)
  //   totals @524288 (4096) | cstart @528384 (4096)
  //   permcid @532480 (262144)
  //   packE @794624 (1024) | pack1 @795648 (6144) | pack2 @801792 (8192)
  //   cproj @809984 (524288 f32)
  //   ZERO range (scan_a): pse @1334272 (786432 f32) | psf @2120704 (1572864 f32)
  unsigned* ws      = (unsigned*)d_ws;
  unsigned* hist2d  = ws;
  unsigned* base2d  = ws + 262144;
  unsigned* totals  = ws + 524288;
  unsigned* cstart  = ws + 528384;
  unsigned* permcid = ws + 532480;
  unsigned* packE   = ws + 794624;
  unsigned* pack1   = ws + 795648;
  unsigned* pack2   = ws + 801792;
  float*    cproj   = (float*)(ws + 809984);
  float*    pse     = (float*)(ws + 1334272);
  float*    psf     = (float*)(ws + 2120704);

  k_init   <<<NBLK + 60, 256, 0, stream>>>(clus, hist2d, eW2, W1, W2,
                                           packE, pack1, pack2);
  k_scan_a <<<112, 256, 0, stream>>>(hist2d, base2d, totals, (float4*)pse);
  k_scatter<<<NBLK, 256, 0, stream>>>(clus, base2d, totals, permcid, cstart);
  k_enc_t  <<<NT, 256, 0, stream>>>(pts, permcid, cstart, eW1, eb1, eb2,
                                    packE, pse);
  k_cproj2 <<<CC / 2, 256, 0, stream>>>(pse, W1, b1, cproj);
  k_fc_t   <<<NT, 256, 0, stream>>>(pts, feat, permcid, cstart, b2, cproj,
                                    pack1, pack2, psf);
  k_glob   <<<1024, 256, 0, stream>>>(psf, G1, gb1, G2, gb2, out);
}

// Round 12
// 110.686 us; speedup vs baseline: 1.2779x; 1.0081x over previous
//
#include <hip/hip_runtime.h>
#include <hip/hip_bf16.h>

#define NN 262144
#define CC 4096
#define NBLK 128             // sort blocks
#define PPB (NN / NBLK)      // 2048 points per sort block
#define NT (NN / 64)         // 4096 dense 64-row tiles
#define SLOTS 3              // per-cluster pooling slots (j>=2 -> atomic into slot 2)

typedef __attribute__((ext_vector_type(8))) short bf16x8;
typedef __attribute__((ext_vector_type(4))) float f32x4;

// bf16 pair pack via HW cvt (RNE)
__device__ __forceinline__ unsigned pk2(float a, float b) {
  __hip_bfloat16 ha = __float2bfloat16(a);
  __hip_bfloat16 hb = __float2bfloat16(b);
  unsigned short ua, ub;
  __builtin_memcpy(&ua, &ha, 2);
  __builtin_memcpy(&ub, &hb, 2);
  return (unsigned)ua | ((unsigned)ub << 16);
}

// ---------- fused init: blocks 0..127 = histogram ; 128..187 = weight prepack ----------
__global__ __launch_bounds__(256) void k_init(
    const int* __restrict__ cluster, unsigned* __restrict__ hist2d,
    const float* __restrict__ eW2, const float* __restrict__ W1,
    const float* __restrict__ W2, unsigned* __restrict__ packE,
    unsigned* __restrict__ pack1, unsigned* __restrict__ pack2)
{
  __shared__ unsigned h[CC];
  const int t = threadIdx.x, b = blockIdx.x;
  if (b < NBLK) {                                      // histogram
    for (int q = t; q < CC; q += 256) h[q] = 0u;
    __syncthreads();
    const int base = b * PPB;
#pragma unroll 4
    for (int k = 0; k < PPB; k += 256) atomicAdd(&h[cluster[base + k + t]], 1u);
    __syncthreads();
    for (int q = t; q < CC; q += 256) hist2d[b * CC + q] = h[q];
    return;
  }
  const int id = (b - NBLK) * 256 + t;                 // prepack
  if (id < 1024) {                                     // packE
    const int nt = id >> 8, l = (id >> 2) & 63, v = id & 3;
    const int k0 = (l >> 4) * 8 + 2 * v, col = nt * 16 + (l & 15);
    packE[id] = pk2(eW2[k0 * 64 + col], eW2[(k0 + 1) * 64 + col]);
  } else if (id < 1024 + 6144) {                       // pack1
    const int j = id - 1024;
    const int kk = j >> 11, nt = (j >> 8) & 7, l = (j >> 2) & 63, v = j & 3;
    const int col = nt * 16 + (l & 15);
    float vals[2];
#pragma unroll
    for (int hh = 0; hh < 2; ++hh) {
      const int k = kk * 32 + (l >> 4) * 8 + 2 * v + hh;
      vals[hh] = (k < 64) ? W1[(3 + k) * 128 + col]
               : (k < 67) ? W1[(k - 64) * 128 + col] : 0.f;
    }
    pack1[j] = pk2(vals[0], vals[1]);
  } else {                                             // pack2 (interleaved k)
    const int j = id - (1024 + 6144);
    const int kk = j >> 11, nt = (j >> 8) & 7, l = (j >> 2) & 63, v = j & 3;
    const int col = nt * 16 + (l & 15);
    const int k0 = kk * 32 + (l >> 4) * 4 + v;
    pack2[j] = pk2(W2[k0 * 128 + col], W2[(k0 + 16) * 128 + col]);
  }
}

// ---------- scan_a: per-cluster exclusive scan over 128 sort blocks ----------
__global__ __launch_bounds__(256) void k_scan_a(
    const unsigned* __restrict__ hist2d, unsigned* __restrict__ base2d,
    unsigned* __restrict__ totals)
{
  const int c = blockIdx.x * 256 + threadIdx.x;
  unsigned acc = 0;
#pragma unroll 4
  for (int bb = 0; bb < NBLK; ++bb) {
    const unsigned v = hist2d[bb * CC + c];
    base2d[bb * CC + c] = acc;
    acc += v;
  }
  totals[c] = acc;
}

// ---------- scatter: blocks 0..127 sort-scatter ; 128..223 zero pse+psf ----------
#define ZERO_F4 589824        // (pse 786432 + psf 1572864) u32 / 4
__global__ __launch_bounds__(256) void k_scatter(
    const int* __restrict__ cluster, const unsigned* __restrict__ base2d,
    const unsigned* __restrict__ totals, unsigned* __restrict__ permcid,
    unsigned* __restrict__ cstart_g, float4* __restrict__ zbase)
{
  __shared__ unsigned cur[CC];
  __shared__ unsigned part[256];
  const int t = threadIdx.x, b = blockIdx.x;
  if (b >= NBLK) {                                     // zero pse+psf (hist2d dead)
    const int zb = b - NBLK;
    const float4 z = {0.f, 0.f, 0.f, 0.f};
#pragma unroll 4
    for (int q = 0; q < 24; ++q)
      zbase[(size_t)(zb * 24 + q) * 256 + t] = z;
    return;
  }
  unsigned loc[16];
  unsigned s = 0;
#pragma unroll
  for (int q = 0; q < 16; ++q) { loc[q] = s; s += totals[t * 16 + q]; }
  part[t] = s;
  __syncthreads();
  for (int off = 1; off < 256; off <<= 1) {
    const unsigned v = (t >= off) ? part[t - off] : 0u;
    __syncthreads();
    part[t] += v;
    __syncthreads();
  }
  const unsigned baset = part[t] - s;
#pragma unroll
  for (int q = 0; q < 16; ++q) {
    const unsigned cs = baset + loc[q];
    cur[t * 16 + q] = base2d[b * CC + t * 16 + q] + cs;
    if (b == 0) cstart_g[t * 16 + q] = cs;
  }
  __syncthreads();
  const int base = b * PPB;
#pragma unroll 4
  for (int k = 0; k < PPB; k += 256) {
    const int i = base + k + t;
    const int c = cluster[i];
    const unsigned pos = atomicAdd(&cur[c], 1u);
    permcid[pos] = (unsigned)i | ((unsigned)c << 18);
  }
}

// ---------- tile kernel 1: enc MLP + segmented pool -> pse (plain stores) ----------
__global__ __launch_bounds__(256) void k_enc_t(
    const float* __restrict__ pts, const unsigned* __restrict__ permcid,
    const unsigned* __restrict__ cstart,
    const float* __restrict__ eW1, const float* __restrict__ eb1,
    const float* __restrict__ eb2, const unsigned* __restrict__ packE,
    float* __restrict__ pse)
{
  __shared__ float P4[64 * 4];
  __shared__ unsigned h1s[64 * 20];     // [64][40 bf16] pad -> 2-way max
  __shared__ int seg_r0[65];
  __shared__ int seg_cid[64];
  __shared__ int seg_j[64];
  __shared__ int nseg_s;
  const int t = threadIdx.x;
  const int lane = t & 63, w = t >> 6;
  const int g = lane >> 4, ln15 = lane & 15;
  const int b = blockIdx.x;

  if (w == 0) {   // segment table from sorted cluster ids
    const unsigned pc = permcid[b * 64 + t];
    const int cid = (int)(pc >> 18);
    const int prevcid = (t == 0) ? -1 : (int)(permcid[b * 64 + t - 1] >> 18);
    const bool flag = (t == 0) || (prevcid != cid);
    const unsigned long long mask = __ballot(flag);
    const int rank = (int)__popcll(mask & ((1ull << t) - 1ull));
    if (flag) {
      seg_r0[rank] = t;
      seg_cid[rank] = cid;
      seg_j[rank] = b - (int)(cstart[cid] >> 6);
    }
    if (t == 0) {
      const int ns = (int)__popcll(mask);
      nseg_s = ns;
      seg_r0[ns] = 64;
    }
    const int i = (int)(pc & 0x3FFFFu);
    P4[t * 4 + 0] = pts[i * 3 + 0];
    P4[t * 4 + 1] = pts[i * 3 + 1];
    P4[t * 4 + 2] = pts[i * 3 + 2];
    P4[t * 4 + 3] = 0.f;
  }
  __syncthreads();
  {   // h1 = relu(P @ eW1 + eb1) -> LDS bf16 ; thread: row t>>2, 8 cols
    const int r = t >> 2, qq = t & 3;
    const float p0 = P4[r * 4], p1 = P4[r * 4 + 1], p2 = P4[r * 4 + 2];
    unsigned wv[4];
#pragma unroll
    for (int u = 0; u < 4; ++u) {
      float hv[2];
#pragma unroll
      for (int hh = 0; hh < 2; ++hh) {
        const int cc2 = qq * 8 + 2 * u + hh;
        hv[hh] = fmaxf(fmaf(p2, eW1[64 + cc2],
                       fmaf(p1, eW1[32 + cc2],
                       fmaf(p0, eW1[cc2], eb1[cc2]))), 0.f);
      }
      wv[u] = pk2(hv[0], hv[1]);
    }
    uint4 st; st.x = wv[0]; st.y = wv[1]; st.z = wv[2]; st.w = wv[3];
    *reinterpret_cast<uint4*>(&h1s[r * 20 + qq * 4]) = st;
  }
  __syncthreads();
  {   // enc MFMA: wave w -> cols 16w..16w+15 ; M=64, K=32; segmented pool
    const int col = w * 16 + ln15;
    const bf16x8 bfr = *reinterpret_cast<const bf16x8*>(&packE[(w * 64 + lane) * 4]);
    const float bias = eb2[col];
    f32x4 acc[4];
#pragma unroll
    for (int m = 0; m < 4; ++m) acc[m] = f32x4{bias, bias, bias, bias};
#pragma unroll
    for (int m = 0; m < 4; ++m) {
      const bf16x8 a = *reinterpret_cast<const bf16x8*>(&h1s[(16 * m + ln15) * 20 + g * 4]);
      acc[m] = __builtin_amdgcn_mfma_f32_16x16x32_bf16(a, bfr, acc[m], 0, 0, 0);
    }
    const int nseg = nseg_s;
    for (int s = 0; s < nseg; ++s) {
      const int r0 = seg_r0[s], r1 = seg_r0[s + 1];
      float v = 0.f;    // v >= 0 throughout; final v = max(0, max acc) = relu-max
#pragma unroll
      for (int m = 0; m < 4; ++m) {
        if (r0 < 16 * (m + 1) && r1 > 16 * m) {   // uniform m-block overlap skip
#pragma unroll
          for (int q = 0; q < 4; ++q) {
            const int row = 16 * m + 4 * g + q;
            const bool in = (row >= r0) & (row < r1);
            v = fmaxf(v, in ? acc[m][q] : 0.f);
          }
        }
      }
      v = fmaxf(v, __shfl_xor(v, 16, 64));
      v = fmaxf(v, __shfl_xor(v, 32, 64));
      if (lane < 16) {
        const int c = seg_cid[s], j = seg_j[s];
        if (j < SLOTS - 1)
          pse[((size_t)c * SLOTS + j) * 64 + col] = v;
        else
          atomicMax((int*)&pse[((size_t)c * SLOTS + (SLOTS - 1)) * 64 + col],
                    __float_as_int(v));
      }
    }
  }
}

// ---------- cproj: nm = max-combine(pse) ; cp = b1 + nm @ W1[67:131] ----------
__global__ __launch_bounds__(256) void k_cproj2(
    const float* __restrict__ pse, const float* __restrict__ W1,
    const float* __restrict__ b1, float* __restrict__ cproj)
{
  __shared__ float nm2[2][64];
  const int t = threadIdx.x, b = blockIdx.x;      // 2 clusters per block
  if (t < 128) {
    const int rr = t >> 6, col = t & 63;
    const float* p = pse + ((size_t)(b * 2 + rr) * SLOTS) * 64 + col;
    nm2[rr][col] = fmaxf(fmaxf(p[0], p[64]), p[128]);
  }
  __syncthreads();
  const int rr = t >> 7, col = t & 127;
  const float* __restrict__ Wd = W1 + 67 * 128;
  float a = b1[col];
#pragma unroll 4
  for (int j = 0; j < 16; ++j) {
    const f32x4 nv = *reinterpret_cast<const f32x4*>(&nm2[rr][4 * j]);
    a = fmaf(nv[0], Wd[(4 * j + 0) * 128 + col], a);
    a = fmaf(nv[1], Wd[(4 * j + 1) * 128 + col], a);
    a = fmaf(nv[2], Wd[(4 * j + 2) * 128 + col], a);
    a = fmaf(nv[3], Wd[(4 * j + 3) * 128 + col], a);
  }
  cproj[(size_t)(b * 2 + rr) * 128 + col] = a;
}

// ---------- tile kernel 2: fc1 + fc2 + segmented pool -> psf ----------
__global__ __launch_bounds__(256) void k_fc_t(
    const float* __restrict__ pts, const float* __restrict__ feat,
    const unsigned* __restrict__ permcid, const unsigned* __restrict__ cstart,
    const float* __restrict__ b2, const float* __restrict__ cproj,
    const unsigned* __restrict__ pack1, const unsigned* __restrict__ pack2,
    float* __restrict__ psf)
{
  __shared__ unsigned buf[64 * 68];   // X phase: [64][52] ; E1 phase: [64][68]
  __shared__ int cid_l[64];
  __shared__ int seg_r0[65];
  __shared__ int seg_cid[64];
  __shared__ int seg_j[64];
  __shared__ int nseg_s;
  const int t = threadIdx.x;
  const int lane = t & 63, w = t >> 6;
  const int g = lane >> 4, ln15 = lane & 15;
  const int b = blockIdx.x;

  if (w == 0) {   // segment table (pre-barrier)
    const unsigned pc = permcid[b * 64 + t];
    const int cid = (int)(pc >> 18);
    cid_l[t] = cid;
    const int prevcid = (t == 0) ? -1 : (int)(permcid[b * 64 + t - 1] >> 18);
    const bool flag = (t == 0) || (prevcid != cid);
    const unsigned long long mask = __ballot(flag);
    const int rank = (int)__popcll(mask & ((1ull << t) - 1ull));
    if (flag) {
      seg_r0[rank] = t;
      seg_cid[rank] = cid;
      seg_j[rank] = b - (int)(cstart[cid] >> 6);
    }
    if (t == 0) {
      const int ns = (int)__popcll(mask);
      nseg_s = ns;
      seg_r0[ns] = 64;
    }
  }
  {   // stage X feat cols (bf16): 4 threads/row, 16 cols each
    const int r = t >> 2, seg = t & 3;
    const int i = (int)(permcid[b * 64 + r] & 0x3FFFFu);
    const float4* __restrict__ fp = reinterpret_cast<const float4*>(&feat[(size_t)i * 64 + seg * 16]);
    const float4 f0 = fp[0], f1 = fp[1], f2 = fp[2], f3 = fp[3];
    uint4 s0v, s1v;
    s0v.x = pk2(f0.x, f0.y); s0v.y = pk2(f0.z, f0.w);
    s0v.z = pk2(f1.x, f1.y); s0v.w = pk2(f1.z, f1.w);
    s1v.x = pk2(f2.x, f2.y); s1v.y = pk2(f2.z, f2.w);
    s1v.z = pk2(f3.x, f3.y); s1v.w = pk2(f3.z, f3.w);
    *reinterpret_cast<uint4*>(&buf[r * 52 + seg * 8 + 0]) = s0v;
    *reinterpret_cast<uint4*>(&buf[r * 52 + seg * 8 + 4]) = s1v;
  }
  if (t < 64) {   // X cols 64..66 = pts, 67..95 = 0
    const int i = (int)(permcid[b * 64 + t] & 0x3FFFFu);
    uint4 pw;
    pw.x = pk2(pts[i * 3 + 0], pts[i * 3 + 1]);
    pw.y = pk2(pts[i * 3 + 2], 0.f);
    pw.z = 0u; pw.w = 0u;
    uint4 zz; zz.x = zz.y = zz.z = zz.w = 0u;
    *reinterpret_cast<uint4*>(&buf[t * 52 + 32]) = pw;
    *reinterpret_cast<uint4*>(&buf[t * 52 + 36]) = zz;
    *reinterpret_cast<uint4*>(&buf[t * 52 + 40]) = zz;
    *reinterpret_cast<uint4*>(&buf[t * 52 + 44]) = zz;
  }
  __syncthreads();

  const int colA = w * 32 + ln15, colB = colA + 16;
  f32x4 acc0[4], acc1[4];
  {   // fc1 MFMA: K=96, acc=0; cproj added after (addr known early, loads hoist)
#pragma unroll
    for (int m = 0; m < 4; ++m) {
      acc0[m] = f32x4{0.f, 0.f, 0.f, 0.f};
      acc1[m] = f32x4{0.f, 0.f, 0.f, 0.f};
    }
#pragma unroll
    for (int kk = 0; kk < 3; ++kk) {
      const bf16x8 bf0 = *reinterpret_cast<const bf16x8*>(&pack1[((kk * 8 + 2 * w + 0) * 64 + lane) * 4]);
      const bf16x8 bf1 = *reinterpret_cast<const bf16x8*>(&pack1[((kk * 8 + 2 * w + 1) * 64 + lane) * 4]);
#pragma unroll
      for (int m = 0; m < 4; ++m) {
        const bf16x8 a = *reinterpret_cast<const bf16x8*>(&buf[(16 * m + ln15) * 52 + kk * 16 + g * 4]);
        acc0[m] = __builtin_amdgcn_mfma_f32_16x16x32_bf16(a, bf0, acc0[m], 0, 0, 0);
        acc1[m] = __builtin_amdgcn_mfma_f32_16x16x32_bf16(a, bf1, acc1[m], 0, 0, 0);
      }
    }
#pragma unroll
    for (int m = 0; m < 4; ++m)
#pragma unroll
      for (int q = 0; q < 4; ++q) {
        const int row = 16 * m + 4 * g + q;
        const int cc = cid_l[row];
        acc0[m][q] += cproj[(size_t)cc * 128 + colA];
        acc1[m][q] += cproj[(size_t)cc * 128 + colB];
      }
  }
  __syncthreads();   // all X reads done; buf can be overwritten
  {   // E1 = relu(fc1) as interleaved bf16 pairs: u32 (col, col+16) -> conflict-free
#pragma unroll
    for (int m = 0; m < 4; ++m)
#pragma unroll
      for (int q = 0; q < 4; ++q) {
        const int row = 16 * m + 4 * g + q;
        buf[row * 68 + w * 16 + ln15] =
            pk2(fmaxf(acc0[m][q], 0.f), fmaxf(acc1[m][q], 0.f));
      }
  }
  __syncthreads();
  {   // fc2 MFMA: K=128 (interleaved k matches pack2)
    const float bb0 = b2[colA], bb1 = b2[colB];
#pragma unroll
    for (int m = 0; m < 4; ++m) {
      acc0[m] = f32x4{bb0, bb0, bb0, bb0};
      acc1[m] = f32x4{bb1, bb1, bb1, bb1};
    }
#pragma unroll
    for (int kk = 0; kk < 4; ++kk) {
      const bf16x8 bf0 = *reinterpret_cast<const bf16x8*>(&pack2[((kk * 8 + 2 * w + 0) * 64 + lane) * 4]);
      const bf16x8 bf1 = *reinterpret_cast<const bf16x8*>(&pack2[((kk * 8 + 2 * w + 1) * 64 + lane) * 4]);
#pragma unroll
      for (int m = 0; m < 4; ++m) {
        const bf16x8 a = *reinterpret_cast<const bf16x8*>(&buf[(16 * m + ln15) * 68 + kk * 16 + g * 4]);
        acc0[m] = __builtin_amdgcn_mfma_f32_16x16x32_bf16(a, bf0, acc0[m], 0, 0, 0);
        acc1[m] = __builtin_amdgcn_mfma_f32_16x16x32_bf16(a, bf1, acc1[m], 0, 0, 0);
      }
    }
  }
  {   // segmented pool -> psf (m-block skip + relu folded into max-with-0-init)
    const int nseg = nseg_s;
    for (int s = 0; s < nseg; ++s) {
      const int r0 = seg_r0[s], r1 = seg_r0[s + 1];
      float v0 = 0.f, v1 = 0.f;
#pragma unroll
      for (int m = 0; m < 4; ++m) {
        if (r0 < 16 * (m + 1) && r1 > 16 * m) {   // uniform m-block overlap skip
#pragma unroll
          for (int q = 0; q < 4; ++q) {
            const int row = 16 * m + 4 * g + q;
            const bool in = (row >= r0) & (row < r1);
            v0 = fmaxf(v0, in ? acc0[m][q] : 0.f);
            v1 = fmaxf(v1, in ? acc1[m][q] : 0.f);
          }
        }
      }
      v0 = fmaxf(v0, __shfl_xor(v0, 16, 64)); v0 = fmaxf(v0, __shfl_xor(v0, 32, 64));
      v1 = fmaxf(v1, __shfl_xor(v1, 16, 64)); v1 = fmaxf(v1, __shfl_xor(v1, 32, 64));
      if (lane < 16) {
        const int c = seg_cid[s], j = seg_j[s];
        if (j < SLOTS - 1) {
          psf[((size_t)c * SLOTS + j) * 128 + colA] = v0;
          psf[((size_t)c * SLOTS + j) * 128 + colB] = v1;
        } else {
          atomicMax((int*)&psf[((size_t)c * SLOTS + (SLOTS - 1)) * 128 + colA], __float_as_int(v0));
          atomicMax((int*)&psf[((size_t)c * SLOTS + (SLOTS - 1)) * 128 + colB], __float_as_int(v1));
        }
      }
    }
  }
}

// ---------- global stack: 1024 blocks x 4 clusters, register-blocked f32 ----------
__global__ __launch_bounds__(256) void k_glob(
    const float* __restrict__ psf, const float* __restrict__ G1,
    const float* __restrict__ gb1, const float* __restrict__ G2,
    const float* __restrict__ gb2, float* __restrict__ out)
{
  __shared__ float pooled[4][128];
  __shared__ float tg[4][128];
  const int t = threadIdx.x, b = blockIdx.x;     // 1024 blocks x 4 clusters
  const int c0 = b * 4;
#pragma unroll
  for (int q = 0; q < 2; ++q) {                  // combine SLOTS -> pooled
    const int idx = q * 256 + t;
    const int cc = idx >> 7, col = idx & 127;
    const float* p = psf + (size_t)(c0 + cc) * (SLOTS * 128) + col;
    pooled[cc][col] = fmaxf(fmaxf(p[0], p[128]), p[256]);
  }
  __syncthreads();
  {   // g1: col = t&127; hi = t>>7 selects cluster pair {2hi, 2hi+1}
    const int col = t & 127, hi = t >> 7;
    float a0 = gb1[col], a1 = a0;
#pragma unroll 4
    for (int k = 0; k < 128; ++k) {
      const float wv = G1[k * 128 + col];
      a0 = fmaf(pooled[hi * 2 + 0][k], wv, a0);
      a1 = fmaf(pooled[hi * 2 + 1][k], wv, a1);
    }
    tg[hi * 2 + 0][col] = fmaxf(a0, 0.f);
    tg[hi * 2 + 1][col] = fmaxf(a1, 0.f);
  }
  __syncthreads();
  {   // g2: col = t, 4 clusters; G2 value loaded once per k (LDS reads broadcast)
    float o[4];
#pragma unroll
    for (int q = 0; q < 4; ++q) o[q] = gb2[t];
#pragma unroll 2
    for (int k = 0; k < 128; ++k) {
      const float wv = G2[k * 256 + t];
#pragma unroll
      for (int q = 0; q < 4; ++q) o[q] = fmaf(tg[q][k], wv, o[q]);
    }
#pragma unroll
    for (int q = 0; q < 4; ++q)
      out[(size_t)(c0 + q) * 256 + t] = fmaxf(o[q], 0.f);
  }
}

extern "C" void kernel_launch(void* const* d_in, const int* in_sizes, int n_in,
                              void* d_out, int out_size, void* d_ws, size_t ws_size,
                              hipStream_t stream)
{
  (void)in_sizes; (void)n_in; (void)out_size; (void)ws_size;
  const float* pts  = (const float*)d_in[0];
  const float* feat = (const float*)d_in[1];
  const int*   clus = (const int*)  d_in[2];
  const float* eW1  = (const float*)d_in[3];
  const float* eb1  = (const float*)d_in[4];
  const float* eW2  = (const float*)d_in[5];
  const float* eb2  = (const float*)d_in[6];
  const float* W1   = (const float*)d_in[7];
  const float* b1   = (const float*)d_in[8];
  const float* W2   = (const float*)d_in[9];
  const float* b2   = (const float*)d_in[10];
  const float* G1   = (const float*)d_in[11];
  const float* gb1  = (const float*)d_in[12];
  const float* G2   = (const float*)d_in[13];
  const float* gb2  = (const float*)d_in[14];
  float* out = (float*)d_out;

  // ws layout (u32 offsets), total 14.8 MB:
  //   base2d @0 (524288)
  //   totals @524288 (4096) | cstart @528384 (4096)
  //   permcid @532480 (262144)
  //   packE @794624 (1024) | pack1 @795648 (6144) | pack2 @801792 (8192)
  //   cproj @809984 (524288 f32)
  //   pse @1334272 (786432 f32) | psf @2120704 (1572864 f32)
  //   hist2d ALIASES pse (524288 <= 786432): written by k_init, consumed by
  //   k_scan_a, then dead; k_scatter's zero-blocks overwrite with zeros.
  unsigned* ws      = (unsigned*)d_ws;
  unsigned* base2d  = ws;
  unsigned* totals  = ws + 524288;
  unsigned* cstart  = ws + 528384;
  unsigned* permcid = ws + 532480;
  unsigned* packE   = ws + 794624;
  unsigned* pack1   = ws + 795648;
  unsigned* pack2   = ws + 801792;
  float*    cproj   = (float*)(ws + 809984);
  float*    pse     = (float*)(ws + 1334272);
  float*    psf     = (float*)(ws + 2120704);
  unsigned* hist2d  = ws + 1334272;              // alias pse

  k_init   <<<NBLK + 60, 256, 0, stream>>>(clus, hist2d, eW2, W1, W2,
                                           packE, pack1, pack2);
  k_scan_a <<<CC / 256, 256, 0, stream>>>(hist2d, base2d, totals);
  k_scatter<<<NBLK + 96, 256, 0, stream>>>(clus, base2d, totals, permcid,
                                           cstart, (float4*)pse);
  k_enc_t  <<<NT, 256, 0, stream>>>(pts, permcid, cstart, eW1, eb1, eb2,
                                    packE, pse);
  k_cproj2 <<<CC / 2, 256, 0, stream>>>(pse, W1, b1, cproj);
  k_fc_t   <<<NT, 256, 0, stream>>>(pts, feat, permcid, cstart, b2, cproj,
                                    pack1, pack2, psf);
  k_glob   <<<1024, 256, 0, stream>>>(psf, G1, gb1, G2, gb2, out);
}